// Round 6
// baseline (167.065 us; speedup 1.0000x reference)
//
#include <hip/hip_runtime.h>

// Linear attention via bf16 MFMA:
//   KVT[b][v][d] = sum_k V[b,k,v] * (relu(K[b,k,d])+eps)   (fp32 atomic accumulation)
//   out[b][q,v]  = sum_d (relu(Q[b,q,d])+eps) * KVT[b][v][d]
//
// v7 changes vs v6 (164.8 us; fills at HBM roofline dominate; kernel sum ~35 us):
//  - Drop the fp32 partial buffer + reduce kernel entirely. kvt accumulates its
//    sub-tile directly into a 2 MB fp32 KVT buffer with device-scope atomicAdd
//    (L2-resident; ~16.8 MB L2 traffic vs ~34 MB HBM round-trip + one launch).
//    Buffer zeroed by hipMemsetAsync (graph-capturable; harness uses it too).
//  - out stages the fp32 KVT quarter (L2-hit) and converts to bf16 with the same
//    pack2 RNE during staging. Only fp32 summation order changes (~1e-6 rel).
//  - kvt / out MFMA structure unchanged from v6.

#define BB 8
#define SS 4096
#define DD 256
#define DDV 256
#define EPSF 1e-6f

typedef short bf16x8 __attribute__((ext_vector_type(8)));
typedef float f32x4 __attribute__((ext_vector_type(4)));

__device__ __forceinline__ unsigned int f2bf(float f) {
  unsigned int u = __float_as_uint(f);
  u += 0x7FFF + ((u >> 16) & 1);   // RNE
  return u >> 16;
}
__device__ __forceinline__ unsigned int pack2(float a, float b) {
  return f2bf(a) | (f2bf(b) << 16);
}

// Raw barrier that does NOT drain vmcnt: LDS writes are made visible via
// lgkmcnt(0); outstanding global loads (prefetch) stay in flight.
__device__ __forceinline__ void sync_lds() {
  asm volatile("s_waitcnt lgkmcnt(0)" ::: "memory");
  __builtin_amdgcn_s_barrier();
  __builtin_amdgcn_sched_barrier(0);
}

// ---------------- Kernel A: KVT accumulate ----------------
// grid 8*nchunk*BB = 512, block 512. Per block: 128 v x 64 d, BK=64 pipeline.
// Epilogue: atomicAdd into fp32 KVT[b][v][d].
__global__ __launch_bounds__(512, 4) void kvt_kernel(
    const float* __restrict__ K, const float* __restrict__ V,
    float* __restrict__ kvf, int kchunk) {
  const int nchunk  = SS / kchunk;
  const int nblocks = 8 * nchunk * BB;
  // XCD swizzle: block f runs work w = (f%8)*(nblocks/8) + f/8. The 8 subs
  // (vt,dt) of one (chunk,b) are consecutive w -> same XCD and temporally
  // adjacent, so the K/V slabs are HBM-fetched once and L2-reused.
  const int f  = blockIdx.x;
  const int w  = (f & 7) * (nblocks >> 3) + (f >> 3);
  const int sub   = w & 7;
  const int vt    = sub & 1;    // v half (128 rows)
  const int dt    = sub >> 1;   // d quarter (64 rows)
  const int rest  = w >> 3;
  const int chunk = rest % nchunk;
  const int b     = rest / nchunk;
  const int k0blk = chunk * kchunk;

  __shared__ ushort Vt[2][128 * 64];  // [v][k] swizzled, 2 x 16 KB
  __shared__ ushort Kt[2][64 * 64];   // [d][k] swizzled, 2 x 8 KB

  const int tid  = threadIdx.x;
  const int lane = tid & 63;
  const int wid  = tid >> 6;   // 0..7
  const int wv   = wid >> 2;   // 0..1 (v dir, 64 rows each)
  const int wd   = wid & 3;    // 0..3 (d dir, 16 rows each)
  const int lq   = lane & 15;

  f32x4 acc[4];
  #pragma unroll
  for (int i = 0; i < 4; i++) acc[i] = (f32x4){0.f, 0.f, 0.f, 0.f};

  const float* Vb = V + (size_t)b * SS * DDV + vt * 128;
  const float* Kb = K + (size_t)b * SS * DD + dt * 64;

  // staging coordinates (fixed per thread):
  //   V: 128 rows x 8 octets = 1024 tasks -> 2 per thread
  //   K:  64 rows x 8 octets =  512 tasks -> 1 per thread
  const int rv = tid & 127, obv = tid >> 7;  // 0..3, p adds 4
  const int rk = tid & 63,  obk = tid >> 6;  // 0..7

  float fV[2][8];
  float fK[8];

  auto issue = [&](int kk) {
    #pragma unroll
    for (int p = 0; p < 2; p++) {
      const int o = obv + p * 4;
      #pragma unroll
      for (int j = 0; j < 8; j++)
        fV[p][j] = Vb[(size_t)(k0blk + kk + o * 8 + j) * DDV + rv];
    }
    #pragma unroll
    for (int j = 0; j < 8; j++)
      fK[j] = Kb[(size_t)(k0blk + kk + obk * 8 + j) * DD + rk];
    __builtin_amdgcn_sched_barrier(0);  // pin loads here (prefetch position)
  };

  auto packwrite = [&](int buf) {
    #pragma unroll
    for (int p = 0; p < 2; p++) {
      const int o = obv + p * 4;
      uint4 wq;
      wq.x = pack2(fV[p][0], fV[p][1]); wq.y = pack2(fV[p][2], fV[p][3]);
      wq.z = pack2(fV[p][4], fV[p][5]); wq.w = pack2(fV[p][6], fV[p][7]);
      const int co = o ^ (rv & 7);
      *(uint4*)&Vt[buf][rv * 64 + co * 8] = wq;
    }
    {
      float g[8];
      #pragma unroll
      for (int j = 0; j < 8; j++) g[j] = fmaxf(fK[j], 0.0f) + EPSF;
      uint4 wq;
      wq.x = pack2(g[0], g[1]); wq.y = pack2(g[2], g[3]);
      wq.z = pack2(g[4], g[5]); wq.w = pack2(g[6], g[7]);
      const int co = obk ^ (rk & 7);
      *(uint4*)&Kt[buf][rk * 64 + co * 8] = wq;
    }
  };

  auto mfma_phase = [&](int buf) {
    #pragma unroll
    for (int ks = 0; ks < 2; ks++) {
      const int oct = ks * 4 + (lane >> 4);
      bf16x8 af[4], bfr;
      #pragma unroll
      for (int i = 0; i < 4; i++) {
        const int row = wv * 64 + i * 16 + lq;
        af[i] = *(const bf16x8*)&Vt[buf][row * 64 + (oct ^ (row & 7)) * 8];
      }
      {
        const int row = wd * 16 + lq;
        bfr = *(const bf16x8*)&Kt[buf][row * 64 + (oct ^ (row & 7)) * 8];
      }
      #pragma unroll
      for (int i = 0; i < 4; i++)
        acc[i] = __builtin_amdgcn_mfma_f32_16x16x32_bf16(af[i], bfr, acc[i], 0, 0, 0);
    }
  };

  const int nt = kchunk >> 6;
  issue(0);
  packwrite(0);                 // data-dep vmcnt wait inserted by compiler
  if (nt > 1) issue(64);
  sync_lds();

  int cur = 0;
  for (int t = 0; t < nt; t++) {
    mfma_phase(cur);
    if (t + 1 < nt) {
      packwrite(cur ^ 1);       // tile t+1 (loads issued one full iter ago)
      if (t + 2 < nt) issue((t + 2) << 6);
      sync_lds();
    }
    cur ^= 1;
  }

  // epilogue: atomic fp32 accumulate, KVT layout [v][d]. Device-scope by
  // default (G12); lanes lq consecutive in d -> coalesced atomic bursts.
  float* pb = kvf + (size_t)b * (DD * DDV);
  #pragma unroll
  for (int i = 0; i < 4; i++) {
    const int v = vt * 128 + wv * 64 + i * 16 + ((lane >> 4) << 2);
    const int d = dt * 64 + wd * 16 + lq;
    #pragma unroll
    for (int r = 0; r < 4; r++)
      atomicAdd(&pb[(size_t)(v + r) * DD + d], acc[i][r]);
  }
}

// ---------------- Kernel B: out = (relu(Q)+eps) @ KVT^T ----------------
// grid 1024 (= 4 vt x 32 qt x 8 b, XCD swizzled), block 512 (8 waves).
// Stage fp32 KVT quarter (64v x 256d, L2-resident) into LDS as bf16 (32 KB,
// XOR-swizzled) once, then barrier-free: each wave owns 16 q rows; 8 unrolled
// dc steps of {prefetched global Q loads, 4 swizzled ds_read_b128, 4 MFMA}.
__global__ __launch_bounds__(512, 4) void out_kernel(
    const float* __restrict__ Q, const float* __restrict__ kvf,
    float* __restrict__ out) {
  // XCD swizzle: the 4 vt subs of one (qt,b) are consecutive w -> same XCD,
  // so the shared Q tile is HBM-fetched once. Bucket (128 works) = one b.
  const int f  = blockIdx.x;
  const int w  = (f & 7) * 128 + (f >> 3);   // nblocks = 1024
  const int vt   = w & 3;
  const int rest = w >> 2;     // 0..255
  const int qt   = rest & 31;
  const int b    = rest >> 5;
  const int q0   = qt * 128;

  __shared__ ushort KVs[64 * 256];  // [v-local][d], 16B-chunk XOR swizzle, 32 KB

  const int tid  = threadIdx.x;
  const int lane = tid & 63;
  const int wq   = tid >> 6;           // wave 0..7 -> q sub-tile (16 rows)
  const int lq   = lane & 15;
  const int lk   = (lane >> 4) << 3;   // 0,8,16,24

  const float* Qw = Q + ((size_t)b * SS + q0 + wq * 16) * DD;

  // prefetch first Q fragment (raw) before staging; sync_lds won't drain it
  float4 x0 = *(const float4*)&Qw[(size_t)lq * DD + lk];
  float4 y0 = *(const float4*)&Qw[(size_t)lq * DD + lk + 4];

  // ---- stage fp32 KVT quarter into LDS as bf16 (swizzled dest) ----
  {
    const float* src = kvf + (size_t)b * DD * DDV + (size_t)vt * 64 * DD;
    #pragma unroll
    for (int p = 0; p < 4; p++) {
      const int chunk = p * 512 + tid;     // 2048 chunks of 8 values
      const int row = chunk >> 5;          // 0..63 (v-local)
      const int c   = chunk & 31;          // 8-value chunk within row
      const float* s = &src[row * DD + c * 8];
      float4 a = *(const float4*)s;
      float4 d = *(const float4*)(s + 4);
      uint4 val;
      val.x = pack2(a.x, a.y); val.y = pack2(a.z, a.w);
      val.z = pack2(d.x, d.y); val.w = pack2(d.z, d.w);
      const int cs = c ^ (row & 7);
      *(uint4*)&KVs[row * DD + cs * 8] = val;
    }
  }

  f32x4 acc[4];
  #pragma unroll
  for (int j = 0; j < 4; j++) acc[j] = (f32x4){0.f, 0.f, 0.f, 0.f};

  sync_lds();

  #pragma unroll
  for (int s = 0; s < 8; s++) {
    float4 xn, yn;
    if (s < 7) {
      const float* p = &Qw[(size_t)lq * DD + (s + 1) * 32 + lk];
      xn = *(const float4*)p;
      yn = *(const float4*)(p + 4);
    }
    uint4 u;
    u.x = pack2(fmaxf(x0.x, 0.f) + EPSF, fmaxf(x0.y, 0.f) + EPSF);
    u.y = pack2(fmaxf(x0.z, 0.f) + EPSF, fmaxf(x0.w, 0.f) + EPSF);
    u.z = pack2(fmaxf(y0.x, 0.f) + EPSF, fmaxf(y0.y, 0.f) + EPSF);
    u.w = pack2(fmaxf(y0.z, 0.f) + EPSF, fmaxf(y0.w, 0.f) + EPSF);
    const bf16x8 af = *(bf16x8*)&u;

    bf16x8 bfr[4];
    const int oct = s * 4 + (lane >> 4);
    #pragma unroll
    for (int j = 0; j < 4; j++) {
      const int row = j * 16 + lq;
      bfr[j] = *(const bf16x8*)&KVs[row * DD + ((oct ^ (row & 7)) << 3)];
    }
    #pragma unroll
    for (int j = 0; j < 4; j++)
      acc[j] = __builtin_amdgcn_mfma_f32_16x16x32_bf16(af, bfr[j], acc[j], 0, 0, 0);

    x0 = xn; y0 = yn;
  }

  float* ob = out + ((size_t)b * SS + q0 + wq * 16) * DDV;
  const int qr = (lane >> 4) << 2;
  #pragma unroll
  for (int j = 0; j < 4; j++) {
    const int v = vt * 64 + j * 16 + lq;
    #pragma unroll
    for (int r = 0; r < 4; r++)
      ob[(size_t)(qr + r) * DDV + v] = acc[j][r];
  }
}

extern "C" void kernel_launch(void* const* d_in, const int* in_sizes, int n_in,
                              void* d_out, int out_size, void* d_ws, size_t ws_size,
                              hipStream_t stream) {
  const float* Q = (const float*)d_in[0];
  const float* K = (const float*)d_in[1];
  const float* V = (const float*)d_in[2];
  float* out = (float*)d_out;

  const size_t N = (size_t)BB * DD * DDV;  // 524288 elements
  float* kvf = (float*)d_ws;               // fp32 KVT accumulator, 2 MB

  // zero the accumulator (workspace arrives poisoned); graph-capturable
  hipMemsetAsync(kvf, 0, N * sizeof(float), stream);

  const int nchunk = 8;
  const int kchunk = SS / nchunk;          // 512
  const int nblocks = 8 * nchunk * BB;     // 512

  kvt_kernel<<<dim3(nblocks), 512, 0, stream>>>(K, V, kvf, kchunk);
  out_kernel<<<dim3(1024), 512, 0, stream>>>(Q, kvf, out);
}

// Round 7
// 153.571 us; speedup vs baseline: 1.0879x; 1.0879x over previous
//
#include <hip/hip_runtime.h>

// Linear attention via bf16 MFMA:
//   KVT[b][v][d] = sum_k V[b,k,v] * (relu(K[b,k,d])+eps)   (fp32 partials over S-chunks)
//   out[b][q,v]  = sum_d (relu(Q[b,q,d])+eps) * KVT[b][v][d]
// All GEMMs use mfma_f32_16x16x32_bf16. LDS tiles are [row][k] with k contiguous
// (ds_read_b128 fragments) and 16B-chunk XOR swizzle (chunk ^= row&7) so both the
// transposed staging writes and the fragment reads run at the bank-conflict floor.
//
// v8 = reversion to the round-0 baseline (best measured: 154.1 / 151.8 us).
// Six structural variants (double-buffered kvt pipeline, LDS-free out, smaller
// tiles, 4-way vt split, atomic accumulation) all measured 155.9-172.7 us.
// rocprof across all rounds shows the timed iteration is dominated by the
// harness's 256 MiB workspace poison fills (~41 us each at 80-84% of HBM peak)
// and reset dispatches; all three kernels here are individually below the fills
// (never in top-5). This configuration is the empirical optimum.

#define BB 8
#define SS 4096
#define DD 256
#define DDV 256
#define EPSF 1e-6f

typedef short bf16x8 __attribute__((ext_vector_type(8)));
typedef float f32x4 __attribute__((ext_vector_type(4)));

__device__ __forceinline__ unsigned int f2bf(float f) {
  unsigned int u = __float_as_uint(f);
  u += 0x7FFF + ((u >> 16) & 1);   // RNE
  return u >> 16;
}
__device__ __forceinline__ unsigned int pack2(float a, float b) {
  return f2bf(a) | (f2bf(b) << 16);
}

// ---------------- Kernel A: KVT partials ----------------
// grid (2 /*v-tile*/, NCHUNK, BB), block 512. Tile: 128 v x 256 d, BK=64.
__global__ __launch_bounds__(512) void kvt_kernel(
    const float* __restrict__ K, const float* __restrict__ V,
    float* __restrict__ part, int kchunk) {
  const int vt    = blockIdx.x;
  const int chunk = blockIdx.y;
  const int b     = blockIdx.z;
  const int k0blk = chunk * kchunk;

  __shared__ ushort Vt[128 * 64];  // [v][k] swizzled, 16 KB
  __shared__ ushort Kt[256 * 64];  // [d][k] swizzled, 32 KB

  const int tid  = threadIdx.x;
  const int lane = tid & 63;
  const int w    = tid >> 6;   // 0..7
  const int wv   = w >> 2;     // 0..1 (v dir)
  const int wd   = w & 3;      // 0..3 (d dir)

  f32x4 acc[4][4];
  #pragma unroll
  for (int i = 0; i < 4; i++)
    #pragma unroll
    for (int j = 0; j < 4; j++)
      acc[i][j] = (f32x4){0.f, 0.f, 0.f, 0.f};

  const float* Vb = V + (size_t)b * SS * DDV + vt * 128;
  const float* Kb = K + (size_t)b * SS * DD;

  for (int kk = 0; kk < kchunk; kk += 64) {
    // ---- stage V tile: 128 rows (v) x 8 octets, transpose via 8 scalar rounds ----
    {
      const int r = tid & 127;
      const int ob = tid >> 7;   // 0..3
      #pragma unroll
      for (int p = 0; p < 2; p++) {
        const int o = ob + p * 4;
        float f[8];
        #pragma unroll
        for (int j = 0; j < 8; j++)
          f[j] = Vb[(size_t)(k0blk + kk + o * 8 + j) * DDV + r];
        uint4 wqv;
        wqv.x = pack2(f[0], f[1]); wqv.y = pack2(f[2], f[3]);
        wqv.z = pack2(f[4], f[5]); wqv.w = pack2(f[6], f[7]);
        const int co = o ^ (r & 7);
        *(uint4*)&Vt[r * 64 + co * 8] = wqv;
      }
    }
    // ---- stage K tile: 256 rows (d) x 8 octets ----
    {
      const int r = tid & 255;
      const int ob = tid >> 8;   // 0..1
      #pragma unroll
      for (int p = 0; p < 4; p++) {
        const int o = ob + p * 2;
        float f[8];
        #pragma unroll
        for (int j = 0; j < 8; j++)
          f[j] = Kb[(size_t)(k0blk + kk + o * 8 + j) * DD + r];
        #pragma unroll
        for (int j = 0; j < 8; j++) f[j] = fmaxf(f[j], 0.0f) + EPSF;
        uint4 wqk;
        wqk.x = pack2(f[0], f[1]); wqk.y = pack2(f[2], f[3]);
        wqk.z = pack2(f[4], f[5]); wqk.w = pack2(f[6], f[7]);
        const int co = o ^ (r & 7);
        *(uint4*)&Kt[r * 64 + co * 8] = wqk;
      }
    }
    __syncthreads();
    // ---- MFMA: 2 k-steps of 32 ----
    #pragma unroll
    for (int ks = 0; ks < 2; ks++) {
      const int oct = ks * 4 + (lane >> 4);
      bf16x8 af[4], bfr[4];
      #pragma unroll
      for (int i = 0; i < 4; i++) {
        const int row = wv * 64 + i * 16 + (lane & 15);
        af[i] = *(const bf16x8*)&Vt[row * 64 + (oct ^ (row & 7)) * 8];
      }
      #pragma unroll
      for (int j = 0; j < 4; j++) {
        const int row = wd * 64 + j * 16 + (lane & 15);
        bfr[j] = *(const bf16x8*)&Kt[row * 64 + (oct ^ (row & 7)) * 8];
      }
      #pragma unroll
      for (int i = 0; i < 4; i++)
        #pragma unroll
        for (int j = 0; j < 4; j++)
          acc[i][j] = __builtin_amdgcn_mfma_f32_16x16x32_bf16(af[i], bfr[j], acc[i][j], 0, 0, 0);
    }
    __syncthreads();
  }

  // epilogue: fp32 partial store, KVT layout [v][d]
  float* pb = part + ((size_t)chunk * BB + b) * (DD * DDV);
  #pragma unroll
  for (int i = 0; i < 4; i++) {
    const int v = vt * 128 + wv * 64 + i * 16 + ((lane >> 4) << 2);
    #pragma unroll
    for (int j = 0; j < 4; j++) {
      const int d = wd * 64 + j * 16 + (lane & 15);
      #pragma unroll
      for (int r = 0; r < 4; r++)
        pb[(size_t)(v + r) * DD + d] = acc[i][j][r];
    }
  }
}

// ---------------- Kernel R: reduce partials -> bf16 KVT ----------------
// grid 512, block 256; each thread: 4 consecutive d.
__global__ __launch_bounds__(256) void reduce_kernel(
    const float* __restrict__ part, ushort* __restrict__ kvb, int nchunk) {
  const size_t N = (size_t)BB * DD * DDV;        // 524288
  const size_t i4 = ((size_t)blockIdx.x * 256 + threadIdx.x) * 4;
  float4 s = make_float4(0.f, 0.f, 0.f, 0.f);
  for (int c = 0; c < nchunk; c++) {
    float4 p = *(const float4*)&part[(size_t)c * N + i4];
    s.x += p.x; s.y += p.y; s.z += p.z; s.w += p.w;
  }
  uint2 o;
  o.x = pack2(s.x, s.y);
  o.y = pack2(s.z, s.w);
  *(uint2*)&kvb[i4] = o;
}

// ---------------- Kernel B: out = (relu(Q)+eps) @ KVT^T ----------------
// grid (32 /*q-tile*/, BB), block 512. Tile: 128 q x 256 v, BK=64 over d.
__global__ __launch_bounds__(512) void out_kernel(
    const float* __restrict__ Q, const ushort* __restrict__ kvb,
    float* __restrict__ out) {
  const int qt = blockIdx.x;
  const int b  = blockIdx.y;
  const int q0 = qt * 128;

  __shared__ ushort Qs[128 * 64];   // [q][d] swizzled, 16 KB
  __shared__ ushort KVs[256 * 64];  // [v][d] swizzled, 32 KB

  const int tid  = threadIdx.x;
  const int lane = tid & 63;
  const int w    = tid >> 6;
  const int wq_  = w >> 2;   // 0..1 (q dir)
  const int wv_  = w & 3;    // 0..3 (v dir)

  f32x4 acc[4][4];
  #pragma unroll
  for (int i = 0; i < 4; i++)
    #pragma unroll
    for (int j = 0; j < 4; j++)
      acc[i][j] = (f32x4){0.f, 0.f, 0.f, 0.f};

  const float* Qb = Q + ((size_t)b * SS + q0) * DD;
  const ushort* KVb = kvb + (size_t)b * DD * DDV;

  for (int dc = 0; dc < DD; dc += 64) {
    // ---- stage Q: 128 q x 64 d, float4 loads, relu+eps+cvt ----
    {
      const int dq = tid & 15;
      int q = tid >> 4;          // 0..31
      #pragma unroll
      for (int p = 0; p < 4; p++, q += 32) {
        float4 f = *(const float4*)&Qb[(size_t)q * DD + dc + dq * 4];
        f.x = fmaxf(f.x, 0.f) + EPSF; f.y = fmaxf(f.y, 0.f) + EPSF;
        f.z = fmaxf(f.z, 0.f) + EPSF; f.w = fmaxf(f.w, 0.f) + EPSF;
        uint2 wp; wp.x = pack2(f.x, f.y); wp.y = pack2(f.z, f.w);
        const int addr = q * 64 + (((dq >> 1) ^ (q & 7)) << 3) + ((dq & 1) << 2);
        *(uint2*)&Qs[addr] = wp;
      }
    }
    // ---- stage KV: 256 v x 64 d bf16, 16B chunks (source-permuted for swizzle) ----
    {
      const int c = tid & 7;
      int row = tid >> 3;        // 0..63
      #pragma unroll
      for (int p = 0; p < 4; p++, row += 64) {
        const int o = c ^ (row & 7);
        uint4 val = *(const uint4*)&KVb[(size_t)row * DD + dc + o * 8];
        *(uint4*)&KVs[row * 64 + c * 8] = val;
      }
    }
    __syncthreads();
    #pragma unroll
    for (int ks = 0; ks < 2; ks++) {
      const int oct = (dc >> 3) + ks * 4 + (lane >> 4);
      const int octl = oct & 7;  // oct within current BK tile
      bf16x8 af[4], bfr[4];
      #pragma unroll
      for (int i = 0; i < 4; i++) {
        const int row = wq_ * 64 + i * 16 + (lane & 15);
        af[i] = *(const bf16x8*)&Qs[row * 64 + (octl ^ (row & 7)) * 8];
      }
      #pragma unroll
      for (int j = 0; j < 4; j++) {
        const int row = wv_ * 64 + j * 16 + (lane & 15);
        bfr[j] = *(const bf16x8*)&KVs[row * 64 + (octl ^ (row & 7)) * 8];
      }
      #pragma unroll
      for (int i = 0; i < 4; i++)
        #pragma unroll
        for (int j = 0; j < 4; j++)
          acc[i][j] = __builtin_amdgcn_mfma_f32_16x16x32_bf16(af[i], bfr[j], acc[i][j], 0, 0, 0);
    }
    __syncthreads();
  }

  float* ob = out + ((size_t)b * SS + q0) * DDV;
  #pragma unroll
  for (int i = 0; i < 4; i++) {
    const int qrow = wq_ * 64 + i * 16 + ((lane >> 4) << 2);
    #pragma unroll
    for (int j = 0; j < 4; j++) {
      const int v = wv_ * 64 + j * 16 + (lane & 15);
      #pragma unroll
      for (int r = 0; r < 4; r++)
        ob[(size_t)(qrow + r) * DDV + v] = acc[i][j][r];
    }
  }
}

extern "C" void kernel_launch(void* const* d_in, const int* in_sizes, int n_in,
                              void* d_out, int out_size, void* d_ws, size_t ws_size,
                              hipStream_t stream) {
  const float* Q = (const float*)d_in[0];
  const float* K = (const float*)d_in[1];
  const float* V = (const float*)d_in[2];
  float* out = (float*)d_out;

  const size_t N = (size_t)BB * DD * DDV;  // 524288 elements
  // ws: [nchunk fp32 partials][bf16 KVT]
  int nchunk = 16;
  while (nchunk > 1 && (size_t)nchunk * N * 4 + N * 2 > ws_size) nchunk >>= 1;
  const int kchunk = SS / nchunk;

  float* part = (float*)d_ws;
  ushort* kvb = (ushort*)(part + (size_t)nchunk * N);

  kvt_kernel<<<dim3(2, nchunk, BB), 512, 0, stream>>>(K, V, part, kchunk);
  reduce_kernel<<<dim3(512), 256, 0, stream>>>(part, kvb, nchunk);
  out_kernel<<<dim3(32, BB), 512, 0, stream>>>(Q, kvb, out);
}